// Round 9
// baseline (184.822 us; speedup 1.0000x reference)
//
#include <hip/hip_runtime.h>

typedef _Float16 half_t;
typedef _Float16 half2_t __attribute__((ext_vector_type(2)));
typedef _Float16 half4_t __attribute__((ext_vector_type(4)));

#define KW   31
#define R    15
#define NP   32
#define HH   512
#define WW   512
#define NB   4

#define TX   16              // thread groups in x, each handles 4 consecutive px
#define TY   16              // thread rows
#define PXW  (TX * 4)        // 64 px wide per block
#define EXT_Y (TY + 2*R)     // 46
#define EXT_X (PXW + 2*R)    // 94 px = 47 half2 dwords used
#define DW_ROW 47
#define DSTRIDE 48           // EVEN (keeps 8B align for b64); phase {0,16} uniform 4/bank = free

// (256,1): (256,2) empirically caps VGPR at 128 and spills (R2/R5).
__global__ __launch_bounds__(256, 1) void defocus_kernel(
    const float* __restrict__ sharp, const float* __restrict__ coc_map,
    float* __restrict__ out)
{
    __shared__ float gT[KW][NP];     // gT[tap][plane]; bank == plane
    __shared__ float bnd[KW];
    __shared__ half2_t tile[3][EXT_Y][DSTRIDE];   // ~26.5 KB

    const int tid = threadIdx.x;

    // ---- per-plane 1-D Gaussian weights (zero-padded to 31, centered at R) ----
    if (tid < NP) {
        const int p = tid;
        const double step = 50.0 / 31.0;
        const float pv = (p == 31) ? 50.0f : (float)((double)p * step);
        #pragma unroll
        for (int j = 0; j < KW; ++j) gT[j][p] = 0.0f;
        if (pv < 0.5f) {
            gT[R][p] = 1.0f;
        } else {
            const double coc   = (double)pv;
            const double sigma = coc / 2.355;
            int k = (int)(2.0 * coc + 1.0);
            if ((k & 1) == 0) k += 1;
            if (k > KW) k = KW;
            const int half = k >> 1;
            float s = 0.0f;
            for (int j = 0; j < k; ++j) {
                double c = (double)(j - half);
                s += (float)exp(-(c * c) / (2.0 * sigma * sigma));
            }
            for (int j = 0; j < k; ++j) {
                double c = (double)(j - half);
                gT[R - half + j][p] = (float)exp(-(c * c) / (2.0 * sigma * sigma)) / s;
            }
        }
    }
    // ---- bucket boundaries, bit-exact float32((planes[i]+planes[i+1])/2) ----
    if (tid < KW) {
        const double step = 50.0 / 31.0;
        const float pa = (float)((double)tid * step);
        const float pb = (tid == 30) ? 50.0f : (float)((double)(tid + 1) * step);
        bnd[tid] = (pa + pb) * 0.5f;
    }

    // ---- stage input tile (+halo) as packed f16 pairs, zero outside image ----
    const int bx = blockIdx.x, by = blockIdx.y, bb = blockIdx.z;
    const int x0 = bx * PXW - R, y0 = by * TY - R;
    for (int idx = tid; idx < EXT_Y * DW_ROW; idx += 256) {
        const int r = idx / DW_ROW, dw = idx - r * DW_ROW;
        const int gy = y0 + r;
        const int gxa = x0 + 2 * dw, gxb = gxa + 1;
        const bool oky = ((unsigned)gy < HH);
        #pragma unroll
        for (int ch = 0; ch < 3; ++ch) {
            const float* src = &sharp[(((size_t)bb * 3 + ch) * HH + gy) * WW];
            const float va = (oky && (unsigned)gxa < WW) ? src[gxa] : 0.0f;
            const float vb = (oky && (unsigned)gxb < WW) ? src[gxb] : 0.0f;
            half2_t h; h.x = (half_t)va; h.y = (half_t)vb;
            tile[ch][r][dw] = h;
        }
    }
    __syncthreads();

    // ---- this thread's 4 pixels ----
    const int tx = tid & (TX - 1), ty = tid >> 4;
    const int ox = bx * PXW + 4 * tx, oy = by * TY + ty;

    // plane select per pixel (exact reference semantics: count coc > bnd[k])
    const float4 coc4 = *(const float4*)&coc_map[((size_t)bb * HH + oy) * WW + ox];
    const float cocv[4] = {coc4.x, coc4.y, coc4.z, coc4.w};
    int plane[4];
    #pragma unroll
    for (int j = 0; j < 4; ++j) {
        int p = 0;
        #pragma unroll
        for (int k = 0; k < KW; ++k) p += (cocv[j] > bnd[k]) ? 1 : 0;
        plane[j] = p;
    }

    // ---- per-pixel x-weights as half2, dword-aligned to the shared window ----
    // window dword k (rel. 2tx) part h = tile px 4tx+2k+h; pixel j tap d = 2k+h-j.
    half2_t wgt[4][16];
    #pragma unroll
    for (int j = 0; j < 4; ++j) {
        const int kmin = j >> 1;
        #pragma unroll
        for (int i = 0; i < 16; ++i) {
            const int k = kmin + i;
            const int d0 = 2 * k - j, d1 = 2 * k + 1 - j;
            half2_t h;
            h.x = (d0 >= 0 && d0 <= 30) ? (half_t)gT[d0][plane[j]] : (half_t)0.0f;
            h.y = (d1 >= 0 && d1 <= 30) ? (half_t)gT[d1][plane[j]] : (half_t)0.0f;
            wgt[j][i] = h;
        }
    }

    // ---- separable accumulation: dy outer (y-weights once), ch inner ----
    float acc[3][4];
    #pragma unroll
    for (int ch = 0; ch < 3; ++ch)
        #pragma unroll
        for (int j = 0; j < 4; ++j) acc[ch][j] = 0.0f;

    #pragma unroll 1
    for (int dy = 0; dy < KW; ++dy) {
        float wy[4];
        #pragma unroll
        for (int j = 0; j < 4; ++j) wy[j] = gT[dy][plane[j]];   // bank==plane
        #pragma unroll
        for (int ch = 0; ch < 3; ++ch) {
            const half2_t* rp = &tile[ch][ty + dy][2 * tx];
            half4_t w4[9];                         // 9 x b64: dw 2tx .. 2tx+17
            #pragma unroll
            for (int k = 0; k < 9; ++k) w4[k] = *(const half4_t*)(rp + 2 * k);
            #pragma unroll
            for (int j = 0; j < 4; ++j) {
                const int kj = j >> 1;
                float s = 0.0f;
                #pragma unroll
                for (int i = 0; i < 16; ++i) {
                    const int kk = kj + i;
                    const half_t d0 = w4[kk >> 1][2 * (kk & 1)];
                    const half_t d1 = w4[kk >> 1][2 * (kk & 1) + 1];
                    // f16 inputs, f32 accumulate -> v_fma_mix_f32 (full rate)
                    s = fmaf((float)wgt[j][i].x, (float)d0, s);
                    s = fmaf((float)wgt[j][i].y, (float)d1, s);
                }
                acc[ch][j] = fmaf(wy[j], s, acc[ch][j]);
            }
        }
    }

    // ---- store 4 px per channel as float4 ----
    #pragma unroll
    for (int ch = 0; ch < 3; ++ch) {
        float* dst = &out[(((size_t)bb * 3 + ch) * HH + oy) * WW + ox];
        *(float4*)dst = make_float4(acc[ch][0], acc[ch][1], acc[ch][2], acc[ch][3]);
    }
}

extern "C" void kernel_launch(void* const* d_in, const int* in_sizes, int n_in,
                              void* d_out, int out_size, void* d_ws, size_t ws_size,
                              hipStream_t stream) {
    const float* sharp = (const float*)d_in[0];
    const float* coc   = (const float*)d_in[1];
    float* outp        = (float*)d_out;
    dim3 grid(WW / PXW, HH / TY, NB);
    defocus_kernel<<<grid, dim3(256), 0, stream>>>(sharp, coc, outp);
}

// Round 10
// 147.787 us; speedup vs baseline: 1.2506x; 1.2506x over previous
//
#include <hip/hip_runtime.h>

typedef _Float16 f16;
typedef _Float16 f16x2 __attribute__((ext_vector_type(2)));
typedef _Float16 f16x8 __attribute__((ext_vector_type(8)));
typedef float    f32x4 __attribute__((ext_vector_type(4)));

#define KW 31
#define R  15
#define NP 32
#define HH 512
#define WW 512
#define NB 4

#define TW 32            // output tile width (px)
#define TH 32            // output tile height
#define EXT_X 62         // TW + 30 data cols
#define SX 80            // tile row stride in f16 (mult of 8 -> 16B-aligned b128 frags)
#define EXT_Y 63         // TH + 30 data rows + 1 pad row (row 62, zeroed)
#define GH_S 81          // gTh row stride (f16): [15+d], d in [-15,65]
#define GY_S 34          // gTy row stride (f16)

__global__ __launch_bounds__(256, 1) void defocus_kernel(
    const float* __restrict__ sharp, const float* __restrict__ coc_map,
    float* __restrict__ out)
{
    __shared__ __align__(16) f16 tile[3][EXT_Y][SX];   // 30.2 KB
    __shared__ __align__(16) f16 gTh[NP][GH_S];        // band-matrix source: [plane][15 + d]
    __shared__ __align__(16) f16 gTy[NP][GY_S];        // y-weights: [plane][dy]
    __shared__ unsigned char pl8[TH][TW];
    __shared__ float bnd[KW];

    const int tid = threadIdx.x;
    const int bx = blockIdx.x, by = blockIdx.y, bb = blockIdx.z;

    // ---- phase 1: per-plane Gaussian weights (f16, zero-padded) + boundaries ----
    if (tid < NP) {
        const int p = tid;
        for (int i = 0; i < GH_S; ++i) gTh[p][i] = (f16)0.0f;
        for (int i = 0; i < GY_S; ++i) gTy[p][i] = (f16)0.0f;
        const double step = 50.0 / 31.0;
        const float pv = (p == 31) ? 50.0f : (float)((double)p * step);
        if (pv < 0.5f) {
            gTh[p][15 + R] = (f16)1.0f;
            gTy[p][R]      = (f16)1.0f;
        } else {
            const double coc   = (double)pv;
            const double sigma = coc / 2.355;
            int k = (int)(2.0 * coc + 1.0);
            if ((k & 1) == 0) k += 1;
            if (k > KW) k = KW;
            const int half = k >> 1;
            float s = 0.0f;
            for (int j = 0; j < k; ++j) {
                double c = (double)(j - half);
                s += (float)exp(-(c * c) / (2.0 * sigma * sigma));
            }
            for (int j = 0; j < k; ++j) {
                double c = (double)(j - half);
                const float w = (float)exp(-(c * c) / (2.0 * sigma * sigma)) / s;
                const int d = R - half + j;           // tap index 0..30
                gTh[p][15 + d] = (f16)w;
                gTy[p][d]      = (f16)w;
            }
        }
    }
    if (tid < KW) {
        const double step = 50.0 / 31.0;
        const float pa = (float)((double)tid * step);
        const float pb = (tid == 30) ? 50.0f : (float)((double)(tid + 1) * step);
        bnd[tid] = (pa + pb) * 0.5f;
    }
    __syncthreads();

    // ---- phase 2a: per-pixel plane selection (exact: count coc > bnd[k]) ----
    {
        const int row = tid >> 3;
        const int x4  = (tid & 7) * 4;
        const float4 c4 = *(const float4*)&coc_map[((size_t)bb * HH + by * TH + row) * WW + bx * TW + x4];
        const float cv[4] = {c4.x, c4.y, c4.z, c4.w};
        int pp[4] = {0, 0, 0, 0};
        #pragma unroll
        for (int k = 0; k < KW; ++k) {
            const float b = bnd[k];
            pp[0] += (cv[0] > b) ? 1 : 0;
            pp[1] += (cv[1] > b) ? 1 : 0;
            pp[2] += (cv[2] > b) ? 1 : 0;
            pp[3] += (cv[3] > b) ? 1 : 0;
        }
        *(uchar4*)&pl8[row][x4] = make_uchar4((unsigned char)pp[0], (unsigned char)pp[1],
                                              (unsigned char)pp[2], (unsigned char)pp[3]);
    }

    // ---- phase 2b: stage tile (+halo) as f16, zero all padding ----
    for (int idx = tid; idx < 3 * EXT_Y * (SX / 2); idx += 256) {
        const int dw = idx % (SX / 2);
        const int rr = (idx / (SX / 2)) % EXT_Y;
        const int ch = idx / ((SX / 2) * EXT_Y);
        const int gy  = by * TH - R + rr;
        const int gxa = bx * TW - R + 2 * dw;
        float va = 0.0f, vb = 0.0f;
        if (rr < 62 && (unsigned)gy < HH) {
            const float* src = &sharp[(((size_t)bb * 3 + ch) * HH + gy) * WW];
            if (2 * dw     < EXT_X && (unsigned)gxa       < WW) va = src[gxa];
            if (2 * dw + 1 < EXT_X && (unsigned)(gxa + 1) < WW) vb = src[gxa + 1];
        }
        f16x2 h; h.x = (f16)va; h.y = (f16)vb;
        *(f16x2*)&tile[ch][rr][2 * dw] = h;
    }
    __syncthreads();

    // ---- phase 3: per-wave GEMM over 16-px row segments ----
    const int lid = tid & 63, wv = tid >> 6;
    const int c = lid & 15, q = lid >> 4;      // c: MFMA 16-dim lane, q: quad

    for (int t = wv; t < 64; t += 4) {          // 64 tasks: 2 x-segs x 32 rows
        const int sx = t >> 5, r = t & 31;
        const int xs = sx * 16;

        // A-fragments (channel-independent): A[m=c][k=q*8+j] = g_plane(c)[k - c]
        const int pm = pl8[r][xs + c];
        f16x8 a0, a1;
        #pragma unroll
        for (int j = 0; j < 8; ++j) {
            a0[j] = gTh[pm][q * 8 + j      - c + 15];
            a1[j] = gTh[pm][q * 8 + j + 32 - c + 15];
        }

        // planes of the 4 pixels this lane owns in D (rows 4q..4q+3)
        const uchar4 p4 = *(const uchar4*)&pl8[r][xs + 4 * q];

        f32x4 d[3][2];
        #pragma unroll
        for (int ch = 0; ch < 3; ++ch) {
            #pragma unroll
            for (int nt = 0; nt < 2; ++nt) {
                // B[k][n=c]: window col = xs + 32s + q*8 + j, row = r + nt*16 + c
                const f16* bp = &tile[ch][r + nt * 16 + c][xs + q * 8];
                const f16x8 b0 = *(const f16x8*)bp;
                const f16x8 b1 = *(const f16x8*)(bp + 32);
                f32x4 acc = {0.f, 0.f, 0.f, 0.f};
                acc = __builtin_amdgcn_mfma_f32_16x16x32_f16(a0, b0, acc, 0, 0, 0);
                acc = __builtin_amdgcn_mfma_f32_16x16x32_f16(a1, b1, acc, 0, 0, 0);
                d[ch][nt] = acc;
            }
        }

        // epilogue: out[m] = sum_dy wy[plane(m)][dy] * S[m][dy]; dy = nt*16 + c
        float vy[3][4];
        #pragma unroll
        for (int i = 0; i < 4; ++i) {
            const int p_i = (i == 0) ? p4.x : (i == 1) ? p4.y : (i == 2) ? p4.z : p4.w;
            const float wy0 = (float)gTy[p_i][c];
            const float wy1 = (c < 15) ? (float)gTy[p_i][16 + c] : 0.0f;
            #pragma unroll
            for (int ch = 0; ch < 3; ++ch)
                vy[ch][i] = d[ch][0][i] * wy0 + d[ch][1][i] * wy1;
        }
        #pragma unroll
        for (int mk = 1; mk <= 8; mk <<= 1) {
            #pragma unroll
            for (int ch = 0; ch < 3; ++ch)
                #pragma unroll
                for (int i = 0; i < 4; ++i)
                    vy[ch][i] += __shfl_xor(vy[ch][i], mk, 64);
        }
        if (c == 0) {
            const int ox = bx * TW + xs + 4 * q;
            const int oy = by * TH + r;
            #pragma unroll
            for (int ch = 0; ch < 3; ++ch) {
                float4 o = make_float4(vy[ch][0], vy[ch][1], vy[ch][2], vy[ch][3]);
                *(float4*)&out[(((size_t)bb * 3 + ch) * HH + oy) * WW + ox] = o;
            }
        }
    }
}

extern "C" void kernel_launch(void* const* d_in, const int* in_sizes, int n_in,
                              void* d_out, int out_size, void* d_ws, size_t ws_size,
                              hipStream_t stream) {
    const float* sharp = (const float*)d_in[0];
    const float* coc   = (const float*)d_in[1];
    float* outp        = (float*)d_out;
    dim3 grid(WW / TW, HH / TH, NB);
    defocus_kernel<<<grid, dim3(256), 0, stream>>>(sharp, coc, outp);
}

// Round 11
// 122.697 us; speedup vs baseline: 1.5063x; 1.2045x over previous
//
#include <hip/hip_runtime.h>

typedef _Float16 f16;
typedef _Float16 f16x2 __attribute__((ext_vector_type(2)));
typedef _Float16 f16x8 __attribute__((ext_vector_type(8)));
typedef float    f32x4 __attribute__((ext_vector_type(4)));

#define KW 31
#define R  15
#define NP 32
#define HH 512
#define WW 512
#define NB 4

#define TW 32            // output tile width (px)
#define TH 32            // output tile height
#define EXT_X 62         // TW + 30 data cols
#define SX 80            // tile row stride in f16 (mult of 8 -> 16B-aligned b128 frags)
#define EXT_Y 63         // TH + 30 data rows + 1 pad row (row 62, zeroed)
#define GH_S 81          // gTh row stride (f16): [15+d], d in [-15,65]
#define GY_S 34          // gTy row stride (f16)

// 16-lane row-sum via DPP row_ror (VALU pipe — NOT ds_bpermute/LDS!)
template<int N>
__device__ __forceinline__ float ror_add(float v) {
    int s = __builtin_amdgcn_update_dpp(0, __float_as_int(v), 0x120 | N, 0xf, 0xf, true);
    return v + __int_as_float(s);
}
__device__ __forceinline__ float rowsum16(float v) {
    v = ror_add<1>(v);
    v = ror_add<2>(v);
    v = ror_add<4>(v);
    v = ror_add<8>(v);
    return v;            // every lane in the 16-lane row holds the row sum
}

__global__ __launch_bounds__(256, 1) void defocus_kernel(
    const float* __restrict__ sharp, const float* __restrict__ coc_map,
    float* __restrict__ out)
{
    __shared__ __align__(16) f16 tile[3][EXT_Y][SX];   // 30.2 KB
    __shared__ __align__(16) f16 gTh[NP][GH_S];        // band-matrix source: [plane][15 + d]
    __shared__ __align__(16) f16 gTy[NP][GY_S];        // y-weights: [plane][dy]
    __shared__ unsigned char pl8[TH][TW];
    __shared__ float bnd[KW];

    const int tid = threadIdx.x;
    const int bx = blockIdx.x, by = blockIdx.y, bb = blockIdx.z;

    // ---- phase 1: per-plane Gaussian weights (f16, zero-padded) + boundaries ----
    if (tid < NP) {
        const int p = tid;
        for (int i = 0; i < GH_S; ++i) gTh[p][i] = (f16)0.0f;
        for (int i = 0; i < GY_S; ++i) gTy[p][i] = (f16)0.0f;
        const double step = 50.0 / 31.0;
        const float pv = (p == 31) ? 50.0f : (float)((double)p * step);
        if (pv < 0.5f) {
            gTh[p][15 + R] = (f16)1.0f;
            gTy[p][R]      = (f16)1.0f;
        } else {
            const double coc   = (double)pv;
            const double sigma = coc / 2.355;
            int k = (int)(2.0 * coc + 1.0);
            if ((k & 1) == 0) k += 1;
            if (k > KW) k = KW;
            const int half = k >> 1;
            float s = 0.0f;
            for (int j = 0; j < k; ++j) {
                double c = (double)(j - half);
                s += (float)exp(-(c * c) / (2.0 * sigma * sigma));
            }
            for (int j = 0; j < k; ++j) {
                double c = (double)(j - half);
                const float w = (float)exp(-(c * c) / (2.0 * sigma * sigma)) / s;
                const int d = R - half + j;           // tap index 0..30
                gTh[p][15 + d] = (f16)w;
                gTy[p][d]      = (f16)w;
            }
        }
    }
    if (tid < KW) {
        const double step = 50.0 / 31.0;
        const float pa = (float)((double)tid * step);
        const float pb = (tid == 30) ? 50.0f : (float)((double)(tid + 1) * step);
        bnd[tid] = (pa + pb) * 0.5f;
    }
    __syncthreads();

    // ---- phase 2a: per-pixel plane selection (exact: count coc > bnd[k]) ----
    {
        const int row = tid >> 3;
        const int x4  = (tid & 7) * 4;
        const float4 c4 = *(const float4*)&coc_map[((size_t)bb * HH + by * TH + row) * WW + bx * TW + x4];
        const float cv[4] = {c4.x, c4.y, c4.z, c4.w};
        int pp[4] = {0, 0, 0, 0};
        #pragma unroll
        for (int k = 0; k < KW; ++k) {
            const float b = bnd[k];
            pp[0] += (cv[0] > b) ? 1 : 0;
            pp[1] += (cv[1] > b) ? 1 : 0;
            pp[2] += (cv[2] > b) ? 1 : 0;
            pp[3] += (cv[3] > b) ? 1 : 0;
        }
        *(uchar4*)&pl8[row][x4] = make_uchar4((unsigned char)pp[0], (unsigned char)pp[1],
                                              (unsigned char)pp[2], (unsigned char)pp[3]);
    }

    // ---- phase 2b: stage tile (+halo) as f16, zero all padding ----
    for (int idx = tid; idx < 3 * EXT_Y * (SX / 2); idx += 256) {
        const int dw = idx % (SX / 2);
        const int rr = (idx / (SX / 2)) % EXT_Y;
        const int ch = idx / ((SX / 2) * EXT_Y);
        const int gy  = by * TH - R + rr;
        const int gxa = bx * TW - R + 2 * dw;
        float va = 0.0f, vb = 0.0f;
        if (rr < 62 && (unsigned)gy < HH) {
            const float* src = &sharp[(((size_t)bb * 3 + ch) * HH + gy) * WW];
            if (2 * dw     < EXT_X && (unsigned)gxa       < WW) va = src[gxa];
            if (2 * dw + 1 < EXT_X && (unsigned)(gxa + 1) < WW) vb = src[gxa + 1];
        }
        f16x2 h; h.x = (f16)va; h.y = (f16)vb;
        *(f16x2*)&tile[ch][rr][2 * dw] = h;
    }
    __syncthreads();

    // ---- phase 3: per-wave GEMM over 16-px row segments ----
    const int lid = tid & 63, wv = tid >> 6;
    const int c = lid & 15, q = lid >> 4;      // c: MFMA 16-dim lane, q: quad

    for (int t = wv; t < 64; t += 4) {          // 64 tasks: 2 x-segs x 32 rows
        const int sx = t >> 5, r = t & 31;
        const int xs = sx * 16;

        // A-fragments (channel-independent): A[m=c][k=q*8+j] = g_plane(c)[k - c]
        const int pm = pl8[r][xs + c];
        f16x8 a0, a1;
        #pragma unroll
        for (int j = 0; j < 8; ++j) {
            a0[j] = gTh[pm][q * 8 + j      - c + 15];
            a1[j] = gTh[pm][q * 8 + j + 32 - c + 15];
        }

        // planes of the 4 pixels this lane owns in D (rows 4q..4q+3)
        const uchar4 p4 = *(const uchar4*)&pl8[r][xs + 4 * q];

        f32x4 d[3][2];
        #pragma unroll
        for (int ch = 0; ch < 3; ++ch) {
            #pragma unroll
            for (int nt = 0; nt < 2; ++nt) {
                // B[k][n=c]: window col = xs + 32s + q*8 + j, row = r + nt*16 + c
                const f16* bp = &tile[ch][r + nt * 16 + c][xs + q * 8];
                const f16x8 b0 = *(const f16x8*)bp;
                const f16x8 b1 = *(const f16x8*)(bp + 32);
                f32x4 acc = {0.f, 0.f, 0.f, 0.f};
                acc = __builtin_amdgcn_mfma_f32_16x16x32_f16(a0, b0, acc, 0, 0, 0);
                acc = __builtin_amdgcn_mfma_f32_16x16x32_f16(a1, b1, acc, 0, 0, 0);
                d[ch][nt] = acc;
            }
        }

        // epilogue: out[m] = sum_dy wy[plane(m)][dy] * S[m][dy]; dy = nt*16 + c
        // reduction over the 16 dy-lanes via DPP row_ror (VALU), not LDS shuffles
        float vy[3][4];
        #pragma unroll
        for (int i = 0; i < 4; ++i) {
            const int p_i = (i == 0) ? p4.x : (i == 1) ? p4.y : (i == 2) ? p4.z : p4.w;
            const float wy0 = (float)gTy[p_i][c];
            const float wy1 = (c < 15) ? (float)gTy[p_i][16 + c] : 0.0f;
            #pragma unroll
            for (int ch = 0; ch < 3; ++ch)
                vy[ch][i] = d[ch][0][i] * wy0 + d[ch][1][i] * wy1;
        }
        #pragma unroll
        for (int ch = 0; ch < 3; ++ch)
            #pragma unroll
            for (int i = 0; i < 4; ++i)
                vy[ch][i] = rowsum16(vy[ch][i]);

        if (c == 0) {
            const int ox = bx * TW + xs + 4 * q;
            const int oy = by * TH + r;
            #pragma unroll
            for (int ch = 0; ch < 3; ++ch) {
                float4 o = make_float4(vy[ch][0], vy[ch][1], vy[ch][2], vy[ch][3]);
                *(float4*)&out[(((size_t)bb * 3 + ch) * HH + oy) * WW + ox] = o;
            }
        }
    }
}

extern "C" void kernel_launch(void* const* d_in, const int* in_sizes, int n_in,
                              void* d_out, int out_size, void* d_ws, size_t ws_size,
                              hipStream_t stream) {
    const float* sharp = (const float*)d_in[0];
    const float* coc   = (const float*)d_in[1];
    float* outp        = (float*)d_out;
    dim3 grid(WW / TW, HH / TH, NB);
    defocus_kernel<<<grid, dim3(256), 0, stream>>>(sharp, coc, outp);
}